// Round 1
// baseline (725.784 us; speedup 1.0000x reference)
//
#include <hip/hip_runtime.h>
#include <math.h>

// Problem: 2-layer GNN (linear -> gather -> scatter-mean -> relu) x2,
// segment-max pool over 64 graphs, 2-layer FC head, log_softmax.
// N=100000 nodes, E=1.6M edges, D=H=128, G=64, OUT=2.
//
// Strategy:
//  - Build dst-CSR once per call (histogram + 2-level scan + fill) so the
//    scatter-mean becomes a conflict-free pull (no float atomics).
//  - GEMM (N x 128 @ 128 x 128): fp32 vector ALU (no fp32 MFMA on CDNA4).
//    128-node tile, W+X staged transposed in LDS -> inner loop is
//    3x ds_read_b128 + 32 v_fma per d (conflict-free reads).
//  - Aggregation: 32 lanes (float4 each) per node, loop CSR edges,
//    coalesced 512B row gathers, fused mean + relu.
//  - Pool: per-graph boundaries from sorted batch, split-16 partial max,
//    fused final-max + FC1 + FC2 + log_softmax kernel.

#define SPLIT 16
#define GP 132   // padded LDS row (nodes/h per d-row); %4==0 for b128 alignment

// ---------------- init ----------------
__global__ void k_init(int* deg, int* gstart, int* gend, int N, int G) {
    int i = blockIdx.x * blockDim.x + threadIdx.x;
    if (i < N) deg[i] = 0;
    if (i < G) { gstart[i] = 0; gend[i] = 0; }
}

// ---------------- CSR build ----------------
__global__ void k_hist(const int* __restrict__ dst, int* __restrict__ deg, int E) {
    int e = blockIdx.x * blockDim.x + threadIdx.x;
    if (e < E) atomicAdd(&deg[dst[e]], 1);
}

__global__ void k_scan1(const int* __restrict__ deg, int* __restrict__ rowstart,
                        int* __restrict__ bsum, int N) {
    __shared__ int sc[256];
    int t = threadIdx.x;
    int base = blockIdx.x * 1024 + t * 4;
    int v0 = (base + 0 < N) ? deg[base + 0] : 0;
    int v1 = (base + 1 < N) ? deg[base + 1] : 0;
    int v2 = (base + 2 < N) ? deg[base + 2] : 0;
    int v3 = (base + 3 < N) ? deg[base + 3] : 0;
    int s = v0 + v1 + v2 + v3;
    sc[t] = s;
    __syncthreads();
    for (int off = 1; off < 256; off <<= 1) {
        int x = 0;
        if (t >= off) x = sc[t - off];
        __syncthreads();
        sc[t] += x;
        __syncthreads();
    }
    int excl = sc[t] - s;   // exclusive prefix within block
    if (base + 0 < N) rowstart[base + 0] = excl;
    if (base + 1 < N) rowstart[base + 1] = excl + v0;
    if (base + 2 < N) rowstart[base + 2] = excl + v0 + v1;
    if (base + 3 < N) rowstart[base + 3] = excl + v0 + v1 + v2;
    if (t == 255) bsum[blockIdx.x] = sc[255];
}

__global__ void k_scan2(int* __restrict__ bsum, int NB) {
    __shared__ int sc[1024];
    int t = threadIdx.x;
    int v = (t < NB) ? bsum[t] : 0;
    sc[t] = v;
    __syncthreads();
    for (int off = 1; off < 1024; off <<= 1) {
        int x = 0;
        if (t >= off) x = sc[t - off];
        __syncthreads();
        sc[t] += x;
        __syncthreads();
    }
    if (t < NB) bsum[t] = sc[t] - v;   // exclusive
}

__global__ void k_scan3(int* __restrict__ rowstart, int* __restrict__ cursor,
                        const int* __restrict__ bsum, int N) {
    int base = blockIdx.x * 1024 + threadIdx.x * 4;
    int add = bsum[blockIdx.x];
    #pragma unroll
    for (int k = 0; k < 4; ++k) {
        int n = base + k;
        if (n < N) {
            int r = rowstart[n] + add;
            rowstart[n] = r;
            cursor[n] = r;
        }
    }
}

__global__ void k_fill(const int* __restrict__ src, const int* __restrict__ dst,
                       int* __restrict__ cursor, int* __restrict__ esrc, int E) {
    int e = blockIdx.x * blockDim.x + threadIdx.x;
    if (e < E) {
        int pos = atomicAdd(&cursor[dst[e]], 1);
        esrc[pos] = src[e];
    }
}

// ---------------- GEMM: out[n,h] = bias[h] + sum_d in[n,d]*W[h,d] ----------------
// 512 threads, 128-node x 128-h tile. X and W staged transposed ([d][n]/[d][h])
// so the d-loop reads are ds_read_b128 conflict-free.
__global__ __launch_bounds__(512) void k_gemm(const float* __restrict__ in,
                                              const float* __restrict__ W,
                                              const float* __restrict__ bias,
                                              float* __restrict__ out, int N) {
    __shared__ float sXT[128 * GP];
    __shared__ float sWT[128 * GP];
    int t = threadIdx.x;
    int n0 = blockIdx.x * 128;

    // stage (transpose into LDS)
    #pragma unroll
    for (int it = 0; it < 8; ++it) {
        int lin = it * 2048 + t * 4;
        int r = lin >> 7;       // node (x) or h (W), 0..127
        int c = lin & 127;      // d, multiple of 4
        float4 xv;
        int n = n0 + r;
        if (n < N) xv = *(const float4*)(in + (size_t)n * 128 + c);
        else       xv = make_float4(0.f, 0.f, 0.f, 0.f);
        sXT[(c + 0) * GP + r] = xv.x;
        sXT[(c + 1) * GP + r] = xv.y;
        sXT[(c + 2) * GP + r] = xv.z;
        sXT[(c + 3) * GP + r] = xv.w;
        float4 wv = *(const float4*)(W + r * 128 + c);
        sWT[(c + 0) * GP + r] = wv.x;
        sWT[(c + 1) * GP + r] = wv.y;
        sWT[(c + 2) * GP + r] = wv.z;
        sWT[(c + 3) * GP + r] = wv.w;
    }
    __syncthreads();

    int tn = t & 31;    // node group: nodes tn*4 .. tn*4+3
    int th = t >> 5;    // h group:    h th*8 .. th*8+7
    int h0 = th * 8;

    float acc[4][8];
    #pragma unroll
    for (int i = 0; i < 4; ++i)
        #pragma unroll
        for (int j = 0; j < 8; ++j) acc[i][j] = 0.f;

    #pragma unroll 4
    for (int d = 0; d < 128; ++d) {
        float4 xv = *(const float4*)(&sXT[d * GP + tn * 4]);
        float4 wa = *(const float4*)(&sWT[d * GP + h0]);
        float4 wb = *(const float4*)(&sWT[d * GP + h0 + 4]);
        float xs[4] = {xv.x, xv.y, xv.z, xv.w};
        float ws[8] = {wa.x, wa.y, wa.z, wa.w, wb.x, wb.y, wb.z, wb.w};
        #pragma unroll
        for (int i = 0; i < 4; ++i)
            #pragma unroll
            for (int j = 0; j < 8; ++j)
                acc[i][j] += xs[i] * ws[j];
    }

    float4 ba = *(const float4*)(bias + h0);
    float4 bb = *(const float4*)(bias + h0 + 4);
    #pragma unroll
    for (int i = 0; i < 4; ++i) {
        int n = n0 + tn * 4 + i;
        if (n < N) {
            float4 o0 = make_float4(acc[i][0] + ba.x, acc[i][1] + ba.y,
                                    acc[i][2] + ba.z, acc[i][3] + ba.w);
            float4 o1 = make_float4(acc[i][4] + bb.x, acc[i][5] + bb.y,
                                    acc[i][6] + bb.z, acc[i][7] + bb.w);
            *(float4*)(out + (size_t)n * 128 + h0)     = o0;
            *(float4*)(out + (size_t)n * 128 + h0 + 4) = o1;
        }
    }
}

// ---------------- aggregation: out[n] = relu(mean_{e: dst=n} in[src_e]) ----------------
// 32 lanes (1 float4 each) per node; 8 nodes per 256-thread block.
__global__ void k_agg(const float* __restrict__ in, const int* __restrict__ esrc,
                      const int* __restrict__ rowstart, const int* __restrict__ deg,
                      float* __restrict__ out, int N) {
    int lane = threadIdx.x & 31;
    int grp  = threadIdx.x >> 5;
    int node = blockIdx.x * 8 + grp;
    if (node >= N) return;
    int start = rowstart[node];
    int d = deg[node];
    const float4* in4 = (const float4*)in;
    float4 acc = make_float4(0.f, 0.f, 0.f, 0.f);
    for (int i = 0; i < d; ++i) {
        int s = esrc[start + i];
        float4 v = in4[(size_t)s * 32 + lane];
        acc.x += v.x; acc.y += v.y; acc.z += v.z; acc.w += v.w;
    }
    float dm = fmaxf((float)d, 1.0f);
    float4 r;
    r.x = fmaxf(acc.x / dm, 0.f);
    r.y = fmaxf(acc.y / dm, 0.f);
    r.z = fmaxf(acc.z / dm, 0.f);
    r.w = fmaxf(acc.w / dm, 0.f);
    ((float4*)out)[(size_t)node * 32 + lane] = r;
}

// ---------------- graph boundaries (batch is sorted) ----------------
__global__ void k_bounds(const int* __restrict__ batch, int* __restrict__ gstart,
                         int* __restrict__ gend, int N) {
    int n = blockIdx.x * blockDim.x + threadIdx.x;
    if (n >= N) return;
    int b = batch[n];
    if (n == 0 || batch[n - 1] != b) gstart[b] = n;
    if (n == N - 1 || batch[n + 1] != b) gend[b] = n + 1;
}

// ---------------- partial segment-max ----------------
__global__ void k_pool1(const float* __restrict__ h, const int* __restrict__ gstart,
                        const int* __restrict__ gend, float* __restrict__ pm, int G) {
    int g = blockIdx.x / SPLIT;
    int c = blockIdx.x % SPLIT;
    int t = threadIdx.x;   // feature 0..127
    int s = gstart[g], e = gend[g];
    int len = e - s;
    int chunk = (len + SPLIT - 1) / SPLIT;
    int lo = s + c * chunk;
    int hi = min(lo + chunk, e);
    float m = -INFINITY;
    for (int n = lo; n < hi; ++n)
        m = fmaxf(m, h[(size_t)n * 128 + t]);
    pm[((size_t)g * SPLIT + c) * 128 + t] = m;
}

// ---------------- final max + FC1(relu) + FC2 + log_softmax ----------------
__global__ void k_fc(const float* __restrict__ pm,
                     const float* __restrict__ Wf1, const float* __restrict__ bf1,
                     const float* __restrict__ Wf2, const float* __restrict__ bf2,
                     float* __restrict__ out) {
    __shared__ float sg[128];
    __shared__ float sz[128];
    __shared__ float so[2];
    int g = blockIdx.x;
    int t = threadIdx.x;
    float m = -INFINITY;
    #pragma unroll
    for (int c = 0; c < SPLIT; ++c)
        m = fmaxf(m, pm[((size_t)g * SPLIT + c) * 128 + t]);
    sg[t] = m;
    __syncthreads();
    float z = bf1[t];
    #pragma unroll 4
    for (int d = 0; d < 128; ++d)
        z += sg[d] * Wf1[t * 128 + d];
    sz[t] = fmaxf(z, 0.f);
    __syncthreads();
    if (t < 2) {
        float o = bf2[t];
        for (int d = 0; d < 128; ++d)
            o += sz[d] * Wf2[t * 128 + d];
        so[t] = o;
    }
    __syncthreads();
    if (t == 0) {
        float a = so[0], b = so[1];
        float mx = fmaxf(a, b);
        float ls = mx + logf(expf(a - mx) + expf(b - mx));
        out[g * 2 + 0] = a - ls;
        out[g * 2 + 1] = b - ls;
    }
}

extern "C" void kernel_launch(void* const* d_in, const int* in_sizes, int n_in,
                              void* d_out, int out_size, void* d_ws, size_t ws_size,
                              hipStream_t stream) {
    const float* x   = (const float*)d_in[0];
    const int*   ei  = (const int*)d_in[1];
    const int* batch = (const int*)d_in[2];
    const float* W1  = (const float*)d_in[3];
    const float* b1  = (const float*)d_in[4];
    const float* W2  = (const float*)d_in[5];
    const float* b2  = (const float*)d_in[6];
    const float* Wf1 = (const float*)d_in[7];
    const float* bf1 = (const float*)d_in[8];
    const float* Wf2 = (const float*)d_in[9];
    const float* bf2 = (const float*)d_in[10];

    int N = in_sizes[2];
    int E = in_sizes[1] / 2;
    int G = out_size / 2;
    const int* src = ei;
    const int* dst = ei + E;

    // workspace carve-out (256B aligned): ~111 MB total
    char* p = (char*)d_ws;
    auto alloc = [&](size_t bytes) -> char* {
        char* r = p;
        p += (bytes + 255) & ~(size_t)255;
        return r;
    };
    float* A       = (float*)alloc((size_t)N * 128 * 4);  // xw buffer
    float* B       = (float*)alloc((size_t)N * 128 * 4);  // h buffer
    int* deg       = (int*)alloc((size_t)N * 4);
    int* rowstart  = (int*)alloc((size_t)N * 4);
    int* cursor    = (int*)alloc((size_t)N * 4);
    int* esrc      = (int*)alloc((size_t)E * 4);
    int* bsum      = (int*)alloc(1024 * 4);
    int* gstart    = (int*)alloc((size_t)G * 4);
    int* gend      = (int*)alloc((size_t)G * 4);
    float* pm      = (float*)alloc((size_t)G * SPLIT * 128 * 4);

    int NB = (N + 1023) / 1024;

    // CSR build (reused by both layers) + graph boundaries
    k_init<<<(N + 255) / 256, 256, 0, stream>>>(deg, gstart, gend, N, G);
    k_hist<<<(E + 255) / 256, 256, 0, stream>>>(dst, deg, E);
    k_scan1<<<NB, 256, 0, stream>>>(deg, rowstart, bsum, N);
    k_scan2<<<1, 1024, 0, stream>>>(bsum, NB);
    k_scan3<<<NB, 256, 0, stream>>>(rowstart, cursor, bsum, N);
    k_fill<<<(E + 255) / 256, 256, 0, stream>>>(src, dst, cursor, esrc, E);
    k_bounds<<<(N + 255) / 256, 256, 0, stream>>>(batch, gstart, gend, N);

    // layer 1
    k_gemm<<<(N + 127) / 128, 512, 0, stream>>>(x, W1, b1, A, N);
    k_agg<<<(N + 7) / 8, 256, 0, stream>>>(A, esrc, rowstart, deg, B, N);
    // layer 2
    k_gemm<<<(N + 127) / 128, 512, 0, stream>>>(B, W2, b2, A, N);
    k_agg<<<(N + 7) / 8, 256, 0, stream>>>(A, esrc, rowstart, deg, B, N);
    // pool + head
    k_pool1<<<G * SPLIT, 128, 0, stream>>>(B, gstart, gend, pm, G);
    k_fc<<<G, 128, 0, stream>>>(pm, Wf1, bf1, Wf2, bf2, (float*)d_out);
}

// Round 2
// 591.856 us; speedup vs baseline: 1.2263x; 1.2263x over previous
//
#include <hip/hip_runtime.h>
#include <math.h>

// 2-layer GNN (linear -> gather -> scatter-mean -> relu) x2, segment-max
// pool over 64 graphs, FC head, log_softmax. N=100k, E=1.6M, D=H=128, G=64.
//
// R1 -> R2: k_fill was the top dispatch (130us, WRITE_SIZE 105MB = 16x
// amplification from random 4B scatter over 6.4MB). Replaced hist+scan+fill
// with a bucketed CSR build: all scatters confined to L2-resident windows.
//  - k_count: per-block LDS bucket histogram (bucket = 256 dst nodes)
//  - k_bscan: 1-block scan -> bucket bases/cursors
//  - k_bin:   multisplit; 1 global atomic per bucket per block; packed edges
//  - k_bcsr:  block=bucket counting sort in a 16KB L2-resident window ->
//             esrc/rowstart/deg, coalesced. (also removes k_hist entirely)

#define SPLIT 16
#define GP 132          // padded LDS row in k_gemm; %4==0 keeps b128 alignment
#define BUCKET_SHIFT 8
#define BUCKET_SIZE 256
#define MAXBUCK 512     // >= nbuck = ceil(N/256) = 391
#define BIN_CHUNK 8192

// ---------------- init ----------------
__global__ void k_init(int* bhist, int* gstart, int* gend, int G) {
    int i = threadIdx.x;   // one block of MAXBUCK threads
    if (i < MAXBUCK) bhist[i] = 0;
    if (i < G) { gstart[i] = 0; gend[i] = 0; }
}

// ---------------- bucket histogram ----------------
__global__ void k_count(const int* __restrict__ dst, int* __restrict__ bhist,
                        int E, int nbuck) {
    __shared__ int lh[MAXBUCK];
    for (int i = threadIdx.x; i < nbuck; i += blockDim.x) lh[i] = 0;
    __syncthreads();
    int base = blockIdx.x * BIN_CHUNK;
    int end = min(base + BIN_CHUNK, E);
    for (int e = base + threadIdx.x; e < end; e += blockDim.x)
        atomicAdd(&lh[dst[e] >> BUCKET_SHIFT], 1);
    __syncthreads();
    for (int i = threadIdx.x; i < nbuck; i += blockDim.x)
        if (lh[i]) atomicAdd(&bhist[i], lh[i]);
}

// ---------------- bucket scan (1 block of MAXBUCK threads) ----------------
__global__ void k_bscan(const int* __restrict__ bhist, int* __restrict__ bstart,
                        int* __restrict__ bcur, int E, int nbuck) {
    __shared__ int sc[MAXBUCK];
    int t = threadIdx.x;
    int v = (t < nbuck) ? bhist[t] : 0;
    sc[t] = v;
    __syncthreads();
    for (int off = 1; off < MAXBUCK; off <<= 1) {
        int x = (t >= off) ? sc[t - off] : 0;
        __syncthreads();
        sc[t] += x;
        __syncthreads();
    }
    if (t < nbuck) {
        int ex = sc[t] - v;   // exclusive
        bstart[t] = ex;
        bcur[t] = ex;
    }
    if (t == 0) bstart[nbuck] = E;
}

// ---------------- multisplit binning ----------------
// pack: low 24 bits = src (N < 2^24), high 8 bits = dst & 255
__global__ void k_bin(const int* __restrict__ src, const int* __restrict__ dst,
                      int* __restrict__ bcur, int* __restrict__ staging,
                      int E, int nbuck) {
    __shared__ int lh[MAXBUCK];
    __shared__ int lbase[MAXBUCK];
    __shared__ int lc[MAXBUCK];
    for (int i = threadIdx.x; i < nbuck; i += blockDim.x) { lh[i] = 0; lc[i] = 0; }
    __syncthreads();
    int base = blockIdx.x * BIN_CHUNK;
    int end = min(base + BIN_CHUNK, E);
    for (int e = base + threadIdx.x; e < end; e += blockDim.x)
        atomicAdd(&lh[dst[e] >> BUCKET_SHIFT], 1);
    __syncthreads();
    for (int i = threadIdx.x; i < nbuck; i += blockDim.x)
        if (lh[i]) lbase[i] = atomicAdd(&bcur[i], lh[i]);
    __syncthreads();
    for (int e = base + threadIdx.x; e < end; e += blockDim.x) {
        int d = dst[e];
        int b = d >> BUCKET_SHIFT;
        int pos = lbase[b] + atomicAdd(&lc[b], 1);
        staging[pos] = src[e] | ((d & (BUCKET_SIZE - 1)) << 24);
    }
}

// ---------------- per-bucket counting sort -> CSR ----------------
// block = bucket; window [bstart[b], bstart[b+1]) is ~16KB, L2-resident,
// disjoint per block -> no cross-XCD thrash.
__global__ __launch_bounds__(BUCKET_SIZE) void k_bcsr(
        const int* __restrict__ staging, const int* __restrict__ bstart,
        int* __restrict__ esrc, int* __restrict__ rowstart,
        int* __restrict__ deg, int N) {
    __shared__ int lh[BUCKET_SIZE];
    __shared__ int lrs[BUCKET_SIZE];
    __shared__ int lcur[BUCKET_SIZE];
    int b = blockIdx.x;
    int s = bstart[b], e = bstart[b + 1];
    int t = threadIdx.x;
    lh[t] = 0;
    __syncthreads();
    for (int i = s + t; i < e; i += BUCKET_SIZE)
        atomicAdd(&lh[((unsigned)staging[i]) >> 24], 1);
    __syncthreads();
    int v = lh[t];
    lrs[t] = v;
    __syncthreads();
    for (int off = 1; off < BUCKET_SIZE; off <<= 1) {
        int x = (t >= off) ? lrs[t - off] : 0;
        __syncthreads();
        lrs[t] += x;
        __syncthreads();
    }
    int excl = lrs[t] - v;
    int node = b * BUCKET_SIZE + t;
    if (node < N) { rowstart[node] = s + excl; deg[node] = v; }
    lcur[t] = excl;
    __syncthreads();
    for (int i = s + t; i < e; i += BUCKET_SIZE) {
        int p = staging[i];
        int local = ((unsigned)p) >> 24;
        int pos = atomicAdd(&lcur[local], 1);
        esrc[s + pos] = p & 0xFFFFFF;
    }
}

// ---------------- GEMM: out[n,h] = bias[h] + sum_d in[n,d]*W[h,d] ----------------
__global__ __launch_bounds__(512) void k_gemm(const float* __restrict__ in,
                                              const float* __restrict__ W,
                                              const float* __restrict__ bias,
                                              float* __restrict__ out, int N) {
    __shared__ float sXT[128 * GP];
    __shared__ float sWT[128 * GP];
    int t = threadIdx.x;
    int n0 = blockIdx.x * 128;

    #pragma unroll
    for (int it = 0; it < 8; ++it) {
        int lin = it * 2048 + t * 4;
        int r = lin >> 7;       // node (x) or h (W), 0..127
        int c = lin & 127;      // d, multiple of 4
        float4 xv;
        int n = n0 + r;
        if (n < N) xv = *(const float4*)(in + (size_t)n * 128 + c);
        else       xv = make_float4(0.f, 0.f, 0.f, 0.f);
        sXT[(c + 0) * GP + r] = xv.x;
        sXT[(c + 1) * GP + r] = xv.y;
        sXT[(c + 2) * GP + r] = xv.z;
        sXT[(c + 3) * GP + r] = xv.w;
        float4 wv = *(const float4*)(W + r * 128 + c);
        sWT[(c + 0) * GP + r] = wv.x;
        sWT[(c + 1) * GP + r] = wv.y;
        sWT[(c + 2) * GP + r] = wv.z;
        sWT[(c + 3) * GP + r] = wv.w;
    }
    __syncthreads();

    int tn = t & 31;
    int th = t >> 5;
    int h0 = th * 8;

    float acc[4][8];
    #pragma unroll
    for (int i = 0; i < 4; ++i)
        #pragma unroll
        for (int j = 0; j < 8; ++j) acc[i][j] = 0.f;

    #pragma unroll 4
    for (int d = 0; d < 128; ++d) {
        float4 xv = *(const float4*)(&sXT[d * GP + tn * 4]);
        float4 wa = *(const float4*)(&sWT[d * GP + h0]);
        float4 wb = *(const float4*)(&sWT[d * GP + h0 + 4]);
        float xs[4] = {xv.x, xv.y, xv.z, xv.w};
        float ws[8] = {wa.x, wa.y, wa.z, wa.w, wb.x, wb.y, wb.z, wb.w};
        #pragma unroll
        for (int i = 0; i < 4; ++i)
            #pragma unroll
            for (int j = 0; j < 8; ++j)
                acc[i][j] += xs[i] * ws[j];
    }

    float4 ba = *(const float4*)(bias + h0);
    float4 bb = *(const float4*)(bias + h0 + 4);
    #pragma unroll
    for (int i = 0; i < 4; ++i) {
        int n = n0 + tn * 4 + i;
        if (n < N) {
            float4 o0 = make_float4(acc[i][0] + ba.x, acc[i][1] + ba.y,
                                    acc[i][2] + ba.z, acc[i][3] + ba.w);
            float4 o1 = make_float4(acc[i][4] + bb.x, acc[i][5] + bb.y,
                                    acc[i][6] + bb.z, acc[i][7] + bb.w);
            *(float4*)(out + (size_t)n * 128 + h0)     = o0;
            *(float4*)(out + (size_t)n * 128 + h0 + 4) = o1;
        }
    }
}

// ---------------- aggregation: out[n] = relu(mean_{e: dst=n} in[src_e]) ----------------
__global__ void k_agg(const float* __restrict__ in, const int* __restrict__ esrc,
                      const int* __restrict__ rowstart, const int* __restrict__ deg,
                      float* __restrict__ out, int N) {
    int lane = threadIdx.x & 31;
    int grp  = threadIdx.x >> 5;
    int node = blockIdx.x * 8 + grp;
    if (node >= N) return;
    int start = rowstart[node];
    int d = deg[node];
    const float4* in4 = (const float4*)in;
    float4 acc = make_float4(0.f, 0.f, 0.f, 0.f);
    for (int i = 0; i < d; ++i) {
        int s = esrc[start + i];
        float4 v = in4[(size_t)s * 32 + lane];
        acc.x += v.x; acc.y += v.y; acc.z += v.z; acc.w += v.w;
    }
    float dm = fmaxf((float)d, 1.0f);
    float4 r;
    r.x = fmaxf(acc.x / dm, 0.f);
    r.y = fmaxf(acc.y / dm, 0.f);
    r.z = fmaxf(acc.z / dm, 0.f);
    r.w = fmaxf(acc.w / dm, 0.f);
    ((float4*)out)[(size_t)node * 32 + lane] = r;
}

// ---------------- graph boundaries (batch is sorted) ----------------
__global__ void k_bounds(const int* __restrict__ batch, int* __restrict__ gstart,
                         int* __restrict__ gend, int N) {
    int n = blockIdx.x * blockDim.x + threadIdx.x;
    if (n >= N) return;
    int b = batch[n];
    if (n == 0 || batch[n - 1] != b) gstart[b] = n;
    if (n == N - 1 || batch[n + 1] != b) gend[b] = n + 1;
}

// ---------------- partial segment-max ----------------
__global__ void k_pool1(const float* __restrict__ h, const int* __restrict__ gstart,
                        const int* __restrict__ gend, float* __restrict__ pm, int G) {
    int g = blockIdx.x / SPLIT;
    int c = blockIdx.x % SPLIT;
    int t = threadIdx.x;   // feature 0..127
    int s = gstart[g], e = gend[g];
    int len = e - s;
    int chunk = (len + SPLIT - 1) / SPLIT;
    int lo = s + c * chunk;
    int hi = min(lo + chunk, e);
    float m = -INFINITY;
    for (int n = lo; n < hi; ++n)
        m = fmaxf(m, h[(size_t)n * 128 + t]);
    pm[((size_t)g * SPLIT + c) * 128 + t] = m;
}

// ---------------- final max + FC1(relu) + FC2 + log_softmax ----------------
__global__ void k_fc(const float* __restrict__ pm,
                     const float* __restrict__ Wf1, const float* __restrict__ bf1,
                     const float* __restrict__ Wf2, const float* __restrict__ bf2,
                     float* __restrict__ out) {
    __shared__ float sg[128];
    __shared__ float sz[128];
    __shared__ float so[2];
    int g = blockIdx.x;
    int t = threadIdx.x;
    float m = -INFINITY;
    #pragma unroll
    for (int c = 0; c < SPLIT; ++c)
        m = fmaxf(m, pm[((size_t)g * SPLIT + c) * 128 + t]);
    sg[t] = m;
    __syncthreads();
    float z = bf1[t];
    #pragma unroll 4
    for (int d = 0; d < 128; ++d)
        z += sg[d] * Wf1[t * 128 + d];
    sz[t] = fmaxf(z, 0.f);
    __syncthreads();
    if (t < 2) {
        float o = bf2[t];
        for (int d = 0; d < 128; ++d)
            o += sz[d] * Wf2[t * 128 + d];
        so[t] = o;
    }
    __syncthreads();
    if (t == 0) {
        float a = so[0], b = so[1];
        float mx = fmaxf(a, b);
        float ls = mx + logf(expf(a - mx) + expf(b - mx));
        out[g * 2 + 0] = a - ls;
        out[g * 2 + 1] = b - ls;
    }
}

extern "C" void kernel_launch(void* const* d_in, const int* in_sizes, int n_in,
                              void* d_out, int out_size, void* d_ws, size_t ws_size,
                              hipStream_t stream) {
    const float* x   = (const float*)d_in[0];
    const int*   ei  = (const int*)d_in[1];
    const int* batch = (const int*)d_in[2];
    const float* W1  = (const float*)d_in[3];
    const float* b1  = (const float*)d_in[4];
    const float* W2  = (const float*)d_in[5];
    const float* b2  = (const float*)d_in[6];
    const float* Wf1 = (const float*)d_in[7];
    const float* bf1 = (const float*)d_in[8];
    const float* Wf2 = (const float*)d_in[9];
    const float* bf2 = (const float*)d_in[10];

    int N = in_sizes[2];
    int E = in_sizes[1] / 2;
    int G = out_size / 2;
    const int* src = ei;
    const int* dst = ei + E;
    int nbuck = (N + BUCKET_SIZE - 1) / BUCKET_SIZE;   // 391

    // workspace carve-out (256B aligned)
    char* p = (char*)d_ws;
    auto alloc = [&](size_t bytes) -> char* {
        char* r = p;
        p += (bytes + 255) & ~(size_t)255;
        return r;
    };
    float* A       = (float*)alloc((size_t)N * 128 * 4);  // xw buffer
    float* B       = (float*)alloc((size_t)N * 128 * 4);  // h buffer
    int* deg       = (int*)alloc((size_t)N * 4);
    int* rowstart  = (int*)alloc((size_t)N * 4);
    int* esrc      = (int*)alloc((size_t)E * 4);
    int* staging   = (int*)alloc((size_t)E * 4);
    int* bhist     = (int*)alloc((MAXBUCK + 2) * 4);
    int* bstart    = (int*)alloc((MAXBUCK + 2) * 4);
    int* bcur      = (int*)alloc((MAXBUCK + 2) * 4);
    int* gstart    = (int*)alloc((size_t)G * 4);
    int* gend      = (int*)alloc((size_t)G * 4);
    float* pm      = (float*)alloc((size_t)G * SPLIT * 128 * 4);

    int nchunk = (E + BIN_CHUNK - 1) / BIN_CHUNK;      // 196

    // CSR build (bucketed) + graph boundaries
    k_init<<<1, MAXBUCK, 0, stream>>>(bhist, gstart, gend, G);
    k_count<<<nchunk, 256, 0, stream>>>(dst, bhist, E, nbuck);
    k_bscan<<<1, MAXBUCK, 0, stream>>>(bhist, bstart, bcur, E, nbuck);
    k_bin<<<nchunk, 256, 0, stream>>>(src, dst, bcur, staging, E, nbuck);
    k_bcsr<<<nbuck, BUCKET_SIZE, 0, stream>>>(staging, bstart, esrc, rowstart, deg, N);
    k_bounds<<<(N + 255) / 256, 256, 0, stream>>>(batch, gstart, gend, N);

    // layer 1
    k_gemm<<<(N + 127) / 128, 512, 0, stream>>>(x, W1, b1, A, N);
    k_agg<<<(N + 7) / 8, 256, 0, stream>>>(A, esrc, rowstart, deg, B, N);
    // layer 2
    k_gemm<<<(N + 127) / 128, 512, 0, stream>>>(B, W2, b2, A, N);
    k_agg<<<(N + 7) / 8, 256, 0, stream>>>(A, esrc, rowstart, deg, B, N);
    // pool + head
    k_pool1<<<G * SPLIT, 128, 0, stream>>>(B, gstart, gend, pm, G);
    k_fc<<<G, 128, 0, stream>>>(pm, Wf1, bf1, Wf2, bf2, (float*)d_out);
}